// Round 13
// baseline (437.469 us; speedup 1.0000x reference)
//
#include <hip/hip_runtime.h>
#include <hip/hip_bf16.h>
#include <math.h>

#define H 1024
#define F 3584
#define F2 7168
#define NE 8
#define T 1024

typedef __attribute__((ext_vector_type(4))) float f32x4;
typedef __attribute__((ext_vector_type(8))) short bf16x8;
typedef __attribute__((ext_vector_type(4))) unsigned u32x4;

__device__ inline short f2bf(float f) {
  union { float f; unsigned u; } v; v.f = f;
  unsigned r = (v.u + 0x7FFFu + ((v.u >> 16) & 1u)) >> 16;
  return (short)r;
}

__device__ inline unsigned pkbf(float a, float b) {
  unsigned r;
  asm("v_cvt_pk_bf16_f32 %0, %1, %2" : "=v"(r) : "v"(a), "v"(b));
  return r;
}

#define MFMA16(af, bf, c) __builtin_amdgcn_mfma_f32_16x16x32_bf16((af), (bf), (c), 0, 0, 0)

// convert 8 fp32 (registers, constant base index) -> bf16x8
#define CVT8(dst, arr, o) { union { u32x4 u; bf16x8 h; } cv_; \
    cv_.u[0] = pkbf(arr[(o) + 0], arr[(o) + 1]); \
    cv_.u[1] = pkbf(arr[(o) + 2], arr[(o) + 3]); \
    cv_.u[2] = pkbf(arr[(o) + 4], arr[(o) + 5]); \
    cv_.u[3] = pkbf(arr[(o) + 6], arr[(o) + 7]); \
    dst = cv_.h; }

// ---------------- x -> bf16 prepass ----------------
__global__ __launch_bounds__(256) void cvtx_k(
    const float* __restrict__ x, unsigned short* __restrict__ xb)
{
  int i = (blockIdx.x * 256 + threadIdx.x) * 8;
  f32x4 a = *(const f32x4*)(x + i);
  f32x4 b = *(const f32x4*)(x + i + 4);
  u32x4 o;
  o[0] = pkbf(a[0], a[1]); o[1] = pkbf(a[2], a[3]);
  o[2] = pkbf(b[0], b[1]); o[3] = pkbf(b[2], b[3]);
  *(u32x4*)(xb + i) = o;
}

// ---------------- router: fp64 logits, top-2 ----------------
__global__ __launch_bounds__(64) void router_k(
    const float* __restrict__ x, const float* __restrict__ gw,
    float* __restrict__ logits, int* __restrict__ cnt,
    int* __restrict__ tok_e, int* __restrict__ tok_r, float* __restrict__ tok_w)
{
  int t = blockIdx.x, l = threadIdx.x;
  const float* xr = x + (size_t)t * H;
  double acc[NE];
  #pragma unroll
  for (int e = 0; e < NE; ++e) acc[e] = 0.0;
  for (int j = 0; j < H / 64; ++j) {
    int h = j * 64 + l;
    float xv = xr[h];
    #pragma unroll
    for (int e = 0; e < NE; ++e) acc[e] += (double)xv * (double)gw[e * H + h];
  }
  #pragma unroll
  for (int off = 32; off >= 1; off >>= 1) {
    #pragma unroll
    for (int e = 0; e < NE; ++e) acc[e] += __shfl_down(acc[e], off, 64);
  }
  if (l == 0) {
    float lg[NE];
    #pragma unroll
    for (int e = 0; e < NE; ++e) { lg[e] = (float)acc[e]; logits[t * NE + e] = lg[e]; }
    int i0 = 0;
    for (int e = 1; e < NE; ++e) if (lg[e] > lg[i0]) i0 = e;
    int i1 = (i0 == 0) ? 1 : 0;
    for (int e = 0; e < NE; ++e) if (e != i0 && lg[e] > lg[i1]) i1 = e;
    float w0 = 1.f / (1.f + expf(lg[i1] - lg[i0]));
    float w1 = 1.f / (1.f + expf(lg[i0] - lg[i1]));
    int r0 = atomicAdd(&cnt[i0], 1);
    int r1 = atomicAdd(&cnt[i1], 1);
    tok_e[2 * t] = i0;     tok_r[2 * t] = r0;     tok_w[2 * t] = w0;
    tok_e[2 * t + 1] = i1; tok_r[2 * t + 1] = r1; tok_w[2 * t + 1] = w1;
  }
}

// ---------------- scan + gather list ----------------
__global__ __launch_bounds__(1024) void build_k(
    const int* __restrict__ cnt, int* __restrict__ base,
    const int* __restrict__ tok_e, const int* __restrict__ tok_r,
    const float* __restrict__ tok_w, int* __restrict__ gtok, float* __restrict__ gws)
{
  __shared__ int sb[NE];
  if (threadIdx.x == 0) {
    int s = 0;
    for (int e = 0; e < NE; ++e) { sb[e] = s; base[e] = s; s += cnt[e]; }
  }
  __syncthreads();
  int t = threadIdx.x;
  #pragma unroll
  for (int k = 0; k < 2; ++k) {
    int e = tok_e[2 * t + k];
    int slot = sb[e] + tok_r[2 * t + k];
    gtok[slot] = t;
    gws[slot] = tok_w[2 * t + k];
  }
}

// ---------------- ffn1: NO-LDS register GEMM, M=64, N=128 (64g+64u), BK=32 ----------------
// 1-phase named-register prefetch pinned with sched_barrier(0) (rule #18:
// compiler otherwise sinks the loads and merges bn into bc -- R12's VGPR=68).
__global__ __launch_bounds__(256, 2) void ffn1_k(
    const unsigned short* __restrict__ xb, const float* __restrict__ wgu,
    const int* __restrict__ cnt, const int* __restrict__ base,
    const int* __restrict__ gtok, unsigned short* __restrict__ act)
{
  // 7168 blocks = 8 XCD * 896 (one expert per XCD); per XCD: 56 p * 16 mB, mB fastest
  int wg = (blockIdx.x & 7) * 896 + (blockIdx.x >> 3);
  int mB = wg & 15;
  int rest = wg >> 4;                 // 0..447
  int e = rest / 56, p = rest % 56;
  int n = cnt[e];
  int m0 = mB * 64;
  if (m0 >= n) return;
  int sb = base[e];
  int tid = threadIdx.x;
  int wv = tid >> 6, lane = tid & 63, lr = lane & 15, lg = lane >> 4;

  // B per-lane base: col = p*64 + wv*16 + lr, k = lg*8; frags +0 (gate), +F (up)
  const float* Bq = wgu + (size_t)e * H * F2 + (size_t)(lg * 8) * F2 + p * 64 + wv * 16 + lr;

  // A per-lane row pointers (token gather, clamped), direct-global bf16
  const unsigned short* ax[4];
  #pragma unroll
  for (int mf = 0; mf < 4; ++mf) {
    int sl = m0 + mf * 16 + lr; if (sl >= n) sl = n - 1;
    ax[mf] = xb + (size_t)gtok[sb + sl] * H + lg * 8;
  }

  f32x4 acc[4][2];
  #pragma unroll
  for (int mf = 0; mf < 4; ++mf) { acc[mf][0] = (f32x4)0.f; acc[mf][1] = (f32x4)0.f; }

  float bc[16], bn[16];
  bf16x8 ac[4], an[4];

#define LOADB1(dst, S) { const float* bp_ = Bq + (size_t)(S) * 32 * F2; \
    _Pragma("unroll") for (int j = 0; j < 8; ++j) { \
      dst[j]     = bp_[(size_t)j * F2]; \
      dst[8 + j] = bp_[(size_t)j * F2 + F]; } }
#define LOADA1(dst, S) { _Pragma("unroll") for (int mf = 0; mf < 4; ++mf) \
      dst[mf] = *(const bf16x8*)(ax[mf] + (S) * 32); }

  LOADB1(bc, 0);
  LOADA1(ac, 0);

  for (int s = 0; s < 32; ++s) {
    if (s < 31) {
      LOADB1(bn, s + 1);
      LOADA1(an, s + 1);
      __builtin_amdgcn_sched_barrier(0);   // pin: prefetch issues BEFORE compute
    }
    bf16x8 b0, b1;
    CVT8(b0, bc, 0); CVT8(b1, bc, 8);
    #pragma unroll
    for (int mf = 0; mf < 4; ++mf) {
      acc[mf][0] = MFMA16(ac[mf], b0, acc[mf][0]);
      acc[mf][1] = MFMA16(ac[mf], b1, acc[mf][1]);
    }
    if (s < 31) {
      __builtin_amdgcn_sched_barrier(0);   // keep copies (and their waits) after compute
      #pragma unroll
      for (int i = 0; i < 16; ++i) bc[i] = bn[i];
      #pragma unroll
      for (int mf = 0; mf < 4; ++mf) ac[mf] = an[mf];
    }
  }
#undef LOADB1
#undef LOADA1

  // epilogue: silu(gate)*up; gate cf 0, up cf 1
  #pragma unroll
  for (int mf = 0; mf < 4; ++mf) {
    int fcol = p * 64 + wv * 16 + lr;
    #pragma unroll
    for (int r = 0; r < 4; ++r) {
      int sl = m0 + mf * 16 + lg * 4 + r;
      if (sl < n) {
        float gg = acc[mf][0][r], u = acc[mf][1][r];
        act[(size_t)(sb + sl) * F + fcol] = (unsigned short)f2bf(gg / (1.f + expf(-gg)) * u);
      }
    }
  }
}

// ---------------- ffn2: NO-LDS register GEMM, M=64, N=128, BK=32, K-split x4 ----------------
__global__ __launch_bounds__(256, 2) void ffn2_k(
    const unsigned short* __restrict__ act, const float* __restrict__ wd,
    const int* __restrict__ cnt, const int* __restrict__ base,
    const int* __restrict__ gtok, const float* __restrict__ gws,
    float* __restrict__ out)
{
  // 4096 blocks = 8 XCD * 512 (one expert per XCD): 16 mB * 8 p * 4 kh, mB fastest
  int wg = (blockIdx.x & 7) * 512 + (blockIdx.x >> 3);
  int mB = wg & 15;
  int rest = wg >> 4;                // 0..255
  int p = rest & 7;
  int kh = (rest >> 3) & 3;
  int e = rest >> 5;
  int n = cnt[e];
  int m0 = mB * 64;
  if (m0 >= n) return;
  int sb = base[e];
  int tid = threadIdx.x;
  int wv = tid >> 6, lane = tid & 63, lr = lane & 15, lg = lane >> 4;
  const int kbase = kh * 896;

  const float* Bq = wd + (size_t)e * F * H + (size_t)(kbase + lg * 8) * H + p * 128 + wv * 32 + lr;

  const unsigned short* ax[4];
  #pragma unroll
  for (int mf = 0; mf < 4; ++mf) {
    int sl = m0 + mf * 16 + lr; if (sl >= n) sl = n - 1;
    ax[mf] = act + (size_t)(sb + sl) * F + kbase + lg * 8;
  }

  f32x4 acc[4][2];
  #pragma unroll
  for (int mf = 0; mf < 4; ++mf) { acc[mf][0] = (f32x4)0.f; acc[mf][1] = (f32x4)0.f; }

  float bc[16], bn[16];
  bf16x8 ac[4], an[4];

#define LOADB2(dst, S) { const float* bp_ = Bq + (size_t)(S) * 32 * H; \
    _Pragma("unroll") for (int j = 0; j < 8; ++j) { \
      dst[j]     = bp_[(size_t)j * H]; \
      dst[8 + j] = bp_[(size_t)j * H + 16]; } }
#define LOADA2(dst, S) { _Pragma("unroll") for (int mf = 0; mf < 4; ++mf) \
      dst[mf] = *(const bf16x8*)(ax[mf] + (S) * 32); }

  LOADB2(bc, 0);
  LOADA2(ac, 0);

  for (int s = 0; s < 28; ++s) {
    if (s < 27) {
      LOADB2(bn, s + 1);
      LOADA2(an, s + 1);
      __builtin_amdgcn_sched_barrier(0);
    }
    bf16x8 b0, b1;
    CVT8(b0, bc, 0); CVT8(b1, bc, 8);
    #pragma unroll
    for (int mf = 0; mf < 4; ++mf) {
      acc[mf][0] = MFMA16(ac[mf], b0, acc[mf][0]);
      acc[mf][1] = MFMA16(ac[mf], b1, acc[mf][1]);
    }
    if (s < 27) {
      __builtin_amdgcn_sched_barrier(0);
      #pragma unroll
      for (int i = 0; i < 16; ++i) bc[i] = bn[i];
      #pragma unroll
      for (int mf = 0; mf < 4; ++mf) ac[mf] = an[mf];
    }
  }
#undef LOADB2
#undef LOADA2

  #pragma unroll
  for (int mf = 0; mf < 4; ++mf) {
    #pragma unroll
    for (int cf = 0; cf < 2; ++cf) {
      int col = p * 128 + wv * 32 + cf * 16 + lr;
      #pragma unroll
      for (int r = 0; r < 4; ++r) {
        int sl = m0 + mf * 16 + lg * 4 + r;
        if (sl < n) {
          int slot = sb + sl;
          atomicAdd(&out[(size_t)gtok[slot] * H + col], gws[slot] * acc[mf][cf][r]);
        }
      }
    }
  }
}

extern "C" void kernel_launch(void* const* d_in, const int* in_sizes, int n_in,
                              void* d_out, int out_size, void* d_ws, size_t ws_size,
                              hipStream_t stream)
{
  const float* x   = (const float*)d_in[0];
  const float* gw  = (const float*)d_in[1];
  const float* wgu = (const float*)d_in[2];
  const float* wdn = (const float*)d_in[3];
  float* out = (float*)d_out;
  float* logits = out + (size_t)T * H;

  char* w = (char*)d_ws;
  int*   cnt = (int*)(w);
  int*   bs  = (int*)(w + 32);
  int*   te  = (int*)(w + 64);
  int*   tr  = (int*)(w + 64 + 8192);
  float* tw  = (float*)(w + 64 + 16384);
  int*   gt  = (int*)(w + 64 + 24576);
  float* gwt = (float*)(w + 64 + 32768);
  unsigned short* act = (unsigned short*)(w + 65536);          // 2048 x 3584 bf16 = 14.68 MB
  unsigned short* xb  = (unsigned short*)(w + 14745600);       // 1024 x 1024 bf16 = 2 MB

  hipMemsetAsync(d_out, 0, (size_t)T * H * sizeof(float), stream);
  hipMemsetAsync(cnt, 0, NE * sizeof(int), stream);
  cvtx_k<<<512, 256, 0, stream>>>(x, xb);
  router_k<<<T, 64, 0, stream>>>(x, gw, logits, cnt, te, tr, tw);
  build_k<<<1, 1024, 0, stream>>>(cnt, bs, te, tr, tw, gt, gwt);
  ffn1_k<<<7168, 256, 0, stream>>>(xb, wgu, cnt, bs, gt, act);
  ffn2_k<<<4096, 256, 0, stream>>>(act, wdn, cnt, bs, gt, gwt, out);
}